// Round 1
// baseline (1899.886 us; speedup 1.0000x reference)
//
#include <hip/hip_runtime.h>
#include <hip/hip_bf16.h>
#include <math.h>

#define NB 16384
#define NH 512
#define NM 4
#define NE 8
#define BH (NB * NH)

// ---------- helpers ----------
__device__ __forceinline__ float wred_sum(float v) {
#pragma unroll
  for (int d = 32; d >= 1; d >>= 1) v += __shfl_xor(v, d);
  return v;
}
__device__ __forceinline__ float wred_max(float v) {
#pragma unroll
  for (int d = 32; d >= 1; d >>= 1) v = fmaxf(v, __shfl_xor(v, d));
  return v;
}
__device__ __forceinline__ float sigmoidf_(float x) { return 1.f / (1.f + expf(-x)); }
__device__ __forceinline__ float softplusf_(float x) {
  return fmaxf(x, 0.f) + log1pf(expf(-fabsf(x)));
}
__device__ __forceinline__ float gelu_t(float x) {
  float u = 0.7978845608028654f * (x + 0.044715f * x * x * x);
  return 0.5f * x * (1.f + tanhf(u));
}
__device__ __forceinline__ bool better(float v, int h, float V, int H) {
  return (v > V) || (v == V && h < H);
}

// =====================================================================
// Kernel 1: fused x-side GEMM (7 streams: delta,gamma,kernel,i,f,o,mem)
// + SSM/memory pointwise epilogue. Writes ssm_new (output) and combined (ws).
// Block: 64 rows x (7 streams x 64 h). 256 threads, microtile 16x7, BK=16.
// =====================================================================
__global__ __launch_bounds__(256, 2) void k1_fused_x(
    const float* __restrict__ x, const float* __restrict__ ssm_state,
    const float* __restrict__ memory0, const float* __restrict__ in_proj_w,
    const float* __restrict__ in_proj_b, const float* __restrict__ kernel_w,
    const float* __restrict__ unified, const float* __restrict__ mem_gate_w,
    const float* __restrict__ mem_scales, float* __restrict__ ssm_out,
    float* __restrict__ combined) {
  __shared__ __align__(16) float xs[64][20];
  __shared__ __align__(16) float wsh[448 * 16];  // swizzled float4 slots

  const int tid = threadIdx.x;
  const int tc = tid & 63, rg = tid >> 6;
  const int rb0 = blockIdx.x * 64;
  const int h0 = blockIdx.y * 64;
  const int sx = (tc >> 1) & 3;

  float acc[16][7];
#pragma unroll
  for (int i = 0; i < 16; ++i)
#pragma unroll
    for (int j = 0; j < 7; ++j) acc[i][j] = 0.f;

  for (int k0 = 0; k0 < NH; k0 += 16) {
    // ---- stage x: 64 rows x 16 k = 256 float4, one per thread ----
    {
      int r = tid >> 2, kq = tid & 3;
      float4 v = *(const float4*)(x + (size_t)(rb0 + r) * NH + k0 + kq * 4);
      *(float4*)(&xs[r][kq * 4]) = v;
    }
    // ---- stage W: 448 rows x 16 k = 1792 float4, 7 per thread ----
#pragma unroll
    for (int c4 = 0; c4 < 7; ++c4) {
      int l = tid >> 2, kq = tid & 3;  // local h, k-quad
      int n = c4 * 64 + l;             // virtual col
      const float* wrow;
      switch (c4) {
        case 0: wrow = in_proj_w + (size_t)(h0 + l) * NH; break;           // delta
        case 1: wrow = in_proj_w + (size_t)(512 + h0 + l) * NH; break;     // gamma
        case 2: wrow = kernel_w + (size_t)(h0 + l) * NH; break;            // kernel
        case 3: wrow = mem_gate_w + (size_t)(h0 + l) * NH; break;          // i
        case 4: wrow = mem_gate_w + (size_t)(512 + h0 + l) * NH; break;    // f
        case 5: wrow = mem_gate_w + (size_t)(1024 + h0 + l) * NH; break;   // o
        default: wrow = unified + (size_t)(h0 + l) * 1536; break;          // mem_w
      }
      float4 v = *(const float4*)(wrow + k0 + kq * 4);
      int slot = n * 4 + (kq ^ ((n >> 1) & 3));
      *((float4*)wsh + slot) = v;
    }
    __syncthreads();
    // ---- compute ----
#pragma unroll
    for (int kg = 0; kg < 4; ++kg) {
      float4 wv[7];
#pragma unroll
      for (int j = 0; j < 7; ++j) {
        int n = tc + 64 * j;
        wv[j] = *((const float4*)wsh + n * 4 + (kg ^ sx));
      }
#pragma unroll
      for (int i = 0; i < 16; ++i) {
        float4 xv = *(const float4*)(&xs[rg * 16 + i][kg * 4]);
#pragma unroll
        for (int j = 0; j < 7; ++j) {
          acc[i][j] = fmaf(xv.x, wv[j].x, acc[i][j]);
          acc[i][j] = fmaf(xv.y, wv[j].y, acc[i][j]);
          acc[i][j] = fmaf(xv.z, wv[j].z, acc[i][j]);
          acc[i][j] = fmaf(xv.w, wv[j].w, acc[i][j]);
        }
      }
    }
    __syncthreads();
  }

  // ---- epilogue: SSM + multi-scale memory pointwise ----
  float s0 = mem_scales[0], s1 = mem_scales[1], s2 = mem_scales[2], s3 = mem_scales[3];
  float sm = fmaxf(fmaxf(s0, s1), fmaxf(s2, s3));
  float e0 = expf(s0 - sm), e1 = expf(s1 - sm), e2 = expf(s2 - sm), e3 = expf(s3 - sm);
  float esum = e0 + e1 + e2 + e3;
  float sc0 = e0 / esum, sc1 = e1 / esum, sc2 = e2 / esum, sc3 = e3 / esum;
  float scsum = sc0 + sc1 + sc2 + sc3;

  const int h = h0 + tc;
  const float bd = in_proj_b[h];
  const float bg = in_proj_b[512 + h];
#pragma unroll
  for (int i = 0; i < 16; ++i) {
    int row = rb0 + rg * 16 + i;
    size_t idx = (size_t)row * NH + h;
    float draw = acc[i][0] + bd;
    float graw = acc[i][1] + bg;
    float sp = softplusf_(draw);
    float decay = expf(-sp);
    float kern = acc[i][2];
    float ssm_new = ssm_state[idx] * decay + kern * (1.f - decay) * graw;
    float ig = sigmoidf_(acc[i][3]);
    float fg = sigmoidf_(acc[i][4]);
    float og = sigmoidf_(acc[i][5]);
    float tl = tanhf(acc[i][6]);
    float wm = sc0 * memory0[idx] + sc1 * memory0[(size_t)BH + idx] +
               sc2 * memory0[2 * (size_t)BH + idx] + sc3 * memory0[3 * (size_t)BH + idx];
    float ms = og * (ig * tl * scsum + fg * wm);
    ssm_out[idx] = ssm_new;
    combined[idx] = ssm_new + ms;
  }
}

// =====================================================================
// Kernel 2: LayerNorm stats (mu, rstd) per row of combined
// =====================================================================
__global__ __launch_bounds__(256) void k2_lnstats(const float* __restrict__ comb,
                                                  float* __restrict__ mu,
                                                  float* __restrict__ rsb) {
  int w = threadIdx.x >> 6, lane = threadIdx.x & 63;
  int row = blockIdx.x * 4 + w;
  const float* c = comb + (size_t)row * NH;
  float v[8];
  float s = 0.f;
#pragma unroll
  for (int q = 0; q < 8; ++q) { v[q] = c[lane + 64 * q]; s += v[q]; }
  s = wred_sum(s);
  float m = s * (1.f / 512.f);
  float s2 = 0.f;
#pragma unroll
  for (int q = 0; q < 8; ++q) { float d = v[q] - m; s2 += d * d; }
  s2 = wred_sum(s2);
  if (lane == 0) {
    mu[row] = m;
    rsb[row] = rsqrtf(s2 * (1.f / 512.f) + 1e-5f);
  }
}

// =====================================================================
// Kernel 3: routing GEMM (LN applied on load) + softmax/temp + clamp +
// top-2 (lowest-index tie-break) -> meta {idx1,idx2,q1,q2}
// Block: 32 rows x 512 cols, 256 threads, microtile 8x8, BK=16.
// =====================================================================
__global__ __launch_bounds__(256, 2) void k3_route(
    const float* __restrict__ comb, const float* __restrict__ mu,
    const float* __restrict__ rsb, const float* __restrict__ unified,
    const float* __restrict__ lng, const float* __restrict__ lnb,
    int* __restrict__ i1o, int* __restrict__ i2o, float* __restrict__ q1o,
    float* __restrict__ q2o) {
  __shared__ __align__(16) float xs[32][20];
  __shared__ __align__(16) float wsh[512 * 16];
  __shared__ float mus[32], rss[32];

  const int tid = threadIdx.x;
  const int tc = tid & 63, rg = tid >> 6;
  const int rb0 = blockIdx.x * 32;
  const int sx = (tc >> 1) & 3;

  if (tid < 32) mus[tid] = mu[rb0 + tid];
  else if (tid < 64) rss[tid - 32] = rsb[rb0 + tid - 32];
  __syncthreads();

  float acc[8][8];
#pragma unroll
  for (int i = 0; i < 8; ++i)
#pragma unroll
    for (int j = 0; j < 8; ++j) acc[i][j] = 0.f;

  for (int k0 = 0; k0 < NH; k0 += 16) {
    if (tid < 128) {
      int r = tid >> 2, kq = tid & 3;
      float4 cv = *(const float4*)(comb + (size_t)(rb0 + r) * NH + k0 + kq * 4);
      float4 gv = *(const float4*)(lng + k0 + kq * 4);
      float4 bv = *(const float4*)(lnb + k0 + kq * 4);
      float mm = mus[r], rr = rss[r];
      float4 o;
      o.x = (cv.x - mm) * rr * gv.x + bv.x;
      o.y = (cv.y - mm) * rr * gv.y + bv.y;
      o.z = (cv.z - mm) * rr * gv.z + bv.z;
      o.w = (cv.w - mm) * rr * gv.w + bv.w;
      *(float4*)(&xs[r][kq * 4]) = o;
    }
#pragma unroll
    for (int c4 = 0; c4 < 8; ++c4) {
      int fidx = c4 * 256 + tid;
      int n = fidx >> 2, kq = fidx & 3;
      float4 v = *(const float4*)(unified + (size_t)n * 1536 + 512 + k0 + kq * 4);
      int slot = n * 4 + (kq ^ ((n >> 1) & 3));
      *((float4*)wsh + slot) = v;
    }
    __syncthreads();
#pragma unroll
    for (int kg = 0; kg < 4; ++kg) {
      float4 wv[8];
#pragma unroll
      for (int j = 0; j < 8; ++j) {
        int n = tc + 64 * j;
        wv[j] = *((const float4*)wsh + n * 4 + (kg ^ sx));
      }
#pragma unroll
      for (int i = 0; i < 8; ++i) {
        float4 xv = *(const float4*)(&xs[rg * 8 + i][kg * 4]);
#pragma unroll
        for (int j = 0; j < 8; ++j) {
          acc[i][j] = fmaf(xv.x, wv[j].x, acc[i][j]);
          acc[i][j] = fmaf(xv.y, wv[j].y, acc[i][j]);
          acc[i][j] = fmaf(xv.z, wv[j].z, acc[i][j]);
          acc[i][j] = fmaf(xv.w, wv[j].w, acc[i][j]);
        }
      }
    }
    __syncthreads();
  }

  // epilogue: per-row softmax(logits/0.1), clamp, top-2
#pragma unroll 1
  for (int i = 0; i < 8; ++i) {
    int row = rb0 + rg * 8 + i;
    float z[8];
#pragma unroll
    for (int j = 0; j < 8; ++j) z[j] = acc[i][j] / 0.1f;
    float m = z[0];
#pragma unroll
    for (int j = 1; j < 8; ++j) m = fmaxf(m, z[j]);
    m = wred_max(m);
    float p[8];
    float ssum = 0.f;
#pragma unroll
    for (int j = 0; j < 8; ++j) { p[j] = expf(z[j] - m); ssum += p[j]; }
    ssum = wred_sum(ssum);
    float v1 = -1.f, v2 = -1.f;
    int h1 = 1 << 30, h2 = 1 << 30;
#pragma unroll
    for (int j = 0; j < 8; ++j) {
      float pc = fmaxf(p[j] / ssum, 1e-4f);
      int hh = tc + 64 * j;
      if (better(pc, hh, v1, h1)) { v2 = v1; h2 = h1; v1 = pc; h1 = hh; }
      else if (better(pc, hh, v2, h2)) { v2 = pc; h2 = hh; }
    }
#pragma unroll
    for (int d = 1; d < 64; d <<= 1) {
      float b1v = __shfl_xor(v1, d); int b1h = __shfl_xor(h1, d);
      float b2v = __shfl_xor(v2, d); int b2h = __shfl_xor(h2, d);
      float n1v, n2v; int n1h, n2h;
      if (better(v1, h1, b1v, b1h)) {
        n1v = v1; n1h = h1;
        if (better(v2, h2, b1v, b1h)) { n2v = v2; n2h = h2; }
        else { n2v = b1v; n2h = b1h; }
      } else {
        n1v = b1v; n1h = b1h;
        if (better(b2v, b2h, v1, h1)) { n2v = b2v; n2h = b2h; }
        else { n2v = v1; n2h = h1; }
      }
      v1 = n1v; h1 = n1h; v2 = n2v; h2 = n2h;
    }
    if (tc == 0) {
      float s = v1 + v2;
      i1o[row] = h1; i2o[row] = h2;
      q1o[row] = v1 / s; q2o[row] = v2 / s;
    }
  }
}

// =====================================================================
// Kernel 4: expert output — only the 2 selected columns are nonzero
// =====================================================================
__global__ __launch_bounds__(256) void k4_expert(
    const float* __restrict__ comb, const float* __restrict__ unified,
    const int* __restrict__ i1, const int* __restrict__ i2,
    const float* __restrict__ q1, const float* __restrict__ q2,
    float* __restrict__ eo) {
  int w = threadIdx.x >> 6, lane = threadIdx.x & 63;
  int row = blockIdx.x * 4 + w;
  int h1 = i1[row], h2 = i2[row];
  float a = q1[row], b = q2[row];
  const float* c = comb + (size_t)row * NH;
  const float* w1 = unified + (size_t)h1 * 1536 + 1024;
  const float* w2 = unified + (size_t)h2 * 1536 + 1024;
  float d1 = 0.f, d2 = 0.f;
#pragma unroll
  for (int q = 0; q < 8; ++q) {
    int k = lane + 64 * q;
    float cv = c[k];
    d1 += cv * w1[k];
    d2 += cv * w2[k];
  }
  d1 = wred_sum(d1);
  d2 = wred_sum(d2);
  float e1 = a * d1, e2 = b * d2;
  float* o = eo + (size_t)row * NH;
#pragma unroll
  for (int q = 0; q < 8; ++q) {
    int hh = lane + 64 * q;
    o[hh] = (hh == h1) ? e1 : ((hh == h2) ? e2 : 0.f);
  }
}

// =====================================================================
// Kernel 5: value/policy heads. GEMM [32 x 512] (256 vh | 256 ph) with
// gelu epilogue fused into value/policy dot products + log_softmax/entropy
// =====================================================================
__global__ __launch_bounds__(256, 2) void k5_heads(
    const float* __restrict__ comb, const float* __restrict__ vw1,
    const float* __restrict__ vb1, const float* __restrict__ vw2,
    const float* __restrict__ vb2, const float* __restrict__ pw1,
    const float* __restrict__ pb1, const float* __restrict__ pw2,
    const float* __restrict__ pb2, float* __restrict__ valo,
    float* __restrict__ polo, float* __restrict__ ento) {
  __shared__ __align__(16) float xs[32][20];
  __shared__ __align__(16) float wsh[512 * 16];
  __shared__ float bias_s[512];
  __shared__ float vw2_s[256];
  __shared__ float pw2_s[2048];

  const int tid = threadIdx.x;
  const int tc = tid & 63, rg = tid >> 6;
  const int rb0 = blockIdx.x * 32;
  const int sx = (tc >> 1) & 3;

  bias_s[tid] = vb1[tid & 255];
  if (tid < 256) bias_s[tid] = vb1[tid];
  else bias_s[tid] = 0.f;  // overwritten below
  if (tid < 256) {
    bias_s[tid + 256] = pb1[tid];
    vw2_s[tid] = vw2[tid];
  }
#pragma unroll
  for (int q = 0; q < 8; ++q) pw2_s[tid + 256 * q] = pw2[tid + 256 * q];
  __syncthreads();

  float acc[8][8];
#pragma unroll
  for (int i = 0; i < 8; ++i)
#pragma unroll
    for (int j = 0; j < 8; ++j) acc[i][j] = 0.f;

  for (int k0 = 0; k0 < NH; k0 += 16) {
    if (tid < 128) {
      int r = tid >> 2, kq = tid & 3;
      float4 v = *(const float4*)(comb + (size_t)(rb0 + r) * NH + k0 + kq * 4);
      *(float4*)(&xs[r][kq * 4]) = v;
    }
#pragma unroll
    for (int c4 = 0; c4 < 8; ++c4) {
      int l = tid >> 2, kq = tid & 3;
      int n = c4 * 64 + l;
      const float* src = (c4 < 4) ? (vw1 + (size_t)n * NH) : (pw1 + (size_t)(n - 256) * NH);
      float4 v = *(const float4*)(src + k0 + kq * 4);
      int slot = n * 4 + (kq ^ ((n >> 1) & 3));
      *((float4*)wsh + slot) = v;
    }
    __syncthreads();
#pragma unroll
    for (int kg = 0; kg < 4; ++kg) {
      float4 wv[8];
#pragma unroll
      for (int j = 0; j < 8; ++j) {
        int n = tc + 64 * j;
        wv[j] = *((const float4*)wsh + n * 4 + (kg ^ sx));
      }
#pragma unroll
      for (int i = 0; i < 8; ++i) {
        float4 xv = *(const float4*)(&xs[rg * 8 + i][kg * 4]);
#pragma unroll
        for (int j = 0; j < 8; ++j) {
          acc[i][j] = fmaf(xv.x, wv[j].x, acc[i][j]);
          acc[i][j] = fmaf(xv.y, wv[j].y, acc[i][j]);
          acc[i][j] = fmaf(xv.z, wv[j].z, acc[i][j]);
          acc[i][j] = fmaf(xv.w, wv[j].w, acc[i][j]);
        }
      }
    }
    __syncthreads();
  }

  const float vb2v = vb2[0];
#pragma unroll 1
  for (int i = 0; i < 8; ++i) {
    int row = rb0 + rg * 8 + i;
    float gv[8];
#pragma unroll
    for (int j = 0; j < 8; ++j) gv[j] = gelu_t(acc[i][j] + bias_s[tc + 64 * j]);
    float vp = 0.f;
#pragma unroll
    for (int j = 0; j < 4; ++j) vp += gv[j] * vw2_s[tc + 64 * j];
    vp = wred_sum(vp);
    float val = vp + vb2v;
    float pol[8];
#pragma unroll
    for (int e = 0; e < 8; ++e) {
      float pp = 0.f;
#pragma unroll
      for (int j = 4; j < 8; ++j) pp += gv[j] * pw2_s[e * 256 + tc + 64 * j - 256];
      pp = wred_sum(pp);
      pol[e] = pp + pb2[e];
    }
    float m = pol[0];
#pragma unroll
    for (int e = 1; e < 8; ++e) m = fmaxf(m, pol[e]);
    float se = 0.f;
#pragma unroll
    for (int e = 0; e < 8; ++e) se += expf(pol[e] - m);
    float lse = m + logf(se);
    float ent = 0.f;
#pragma unroll
    for (int e = 0; e < 8; ++e) {
      float lp = pol[e] - lse;
      ent -= expf(lp) * lp;
    }
    if (tc == 0) {
      valo[row] = val;
      ento[row] = ent;
#pragma unroll
      for (int e = 0; e < 8; ++e) polo[(size_t)row * 8 + e] = pol[e];
    }
  }
}

// =====================================================================
extern "C" void kernel_launch(void* const* d_in, const int* in_sizes, int n_in,
                              void* d_out, int out_size, void* d_ws, size_t ws_size,
                              hipStream_t stream) {
  const float* x          = (const float*)d_in[0];
  const float* ssm_state  = (const float*)d_in[1];
  const float* memory0    = (const float*)d_in[2];
  const float* in_proj_w  = (const float*)d_in[3];
  const float* in_proj_b  = (const float*)d_in[4];
  const float* kernel_w   = (const float*)d_in[5];
  const float* unified    = (const float*)d_in[6];
  const float* mem_gate_w = (const float*)d_in[7];
  const float* mem_scales = (const float*)d_in[8];
  const float* ln_g       = (const float*)d_in[9];
  const float* ln_b       = (const float*)d_in[10];
  const float* vw1        = (const float*)d_in[11];
  const float* vb1        = (const float*)d_in[12];
  const float* vw2        = (const float*)d_in[13];
  const float* vb2        = (const float*)d_in[14];
  const float* pw1        = (const float*)d_in[15];
  const float* pb1        = (const float*)d_in[16];
  const float* pw2        = (const float*)d_in[17];
  const float* pb2        = (const float*)d_in[18];

  float* eo  = (float*)d_out;            // [B,H]
  float* ssm = eo + (size_t)BH;          // [B,H]
  float* val = ssm + (size_t)BH;         // [B]
  float* pol = val + NB;                 // [B,E]
  float* ent = pol + (size_t)NB * NE;    // [B]

  float* combined = (float*)d_ws;                // [B,H]
  float* mu = combined + (size_t)BH;             // [B]
  float* rs = mu + NB;                           // [B]
  int* i1 = (int*)(rs + NB);                     // [B]
  int* i2 = i1 + NB;                             // [B]
  float* q1 = (float*)(i2 + NB);                 // [B]
  float* q2 = q1 + NB;                           // [B]

  hipLaunchKernelGGL(k1_fused_x, dim3(NB / 64, NH / 64), dim3(256), 0, stream,
                     x, ssm_state, memory0, in_proj_w, in_proj_b, kernel_w,
                     unified, mem_gate_w, mem_scales, ssm, combined);
  hipLaunchKernelGGL(k2_lnstats, dim3(NB / 4), dim3(256), 0, stream, combined, mu, rs);
  hipLaunchKernelGGL(k3_route, dim3(NB / 32), dim3(256), 0, stream, combined, mu,
                     rs, unified, ln_g, ln_b, i1, i2, q1, q2);
  hipLaunchKernelGGL(k4_expert, dim3(NB / 4), dim3(256), 0, stream, combined,
                     unified, i1, i2, q1, q2, eo);
  hipLaunchKernelGGL(k5_heads, dim3(NB / 32), dim3(256), 0, stream, combined, vw1,
                     vb1, vw2, vb2, pw1, pb1, pw2, pb2, val, pol, ent);
}

// Round 11
// 1009.558 us; speedup vs baseline: 1.8819x; 1.8819x over previous
//
#include <hip/hip_runtime.h>
#include <hip/hip_bf16.h>
#include <hip/hip_fp16.h>
#include <math.h>

#define NB 16384
#define NH 512
#define NM 4
#define NE 8
#define BH (NB * NH)

typedef _Float16 f16x8 __attribute__((ext_vector_type(8)));
typedef float f32x4 __attribute__((ext_vector_type(4)));

// ws layout (new path)
#define OFF_COMB 0ULL
#define OFF_MU   33554432ULL
#define OFF_RS   (OFF_MU + 65536ULL)
#define OFF_I1   (OFF_RS + 65536ULL)
#define OFF_I2   (OFF_I1 + 65536ULL)
#define OFF_Q1   (OFF_I2 + 65536ULL)
#define OFF_Q2   (OFF_Q1 + 65536ULL)
#define OFF_XAH  34603008ULL                 // 128*16 chunks * 8192 B = 16 MB
#define OFF_XAL  (OFF_XAH + 16777216ULL)
#define OFF_WBH  (OFF_XAL + 16777216ULL)     // 32*16 chunks * 7168 B = 3.67 MB
#define OFF_WBL  (OFF_WBH + 3670016ULL)
#define WS_NEED  (OFF_WBL + 3670016ULL)      // 75,497,472 B

// ---------- helpers ----------
__device__ __forceinline__ float wred_sum(float v) {
#pragma unroll
  for (int d = 32; d >= 1; d >>= 1) v += __shfl_xor(v, d);
  return v;
}
__device__ __forceinline__ float wred_max(float v) {
#pragma unroll
  for (int d = 32; d >= 1; d >>= 1) v = fmaxf(v, __shfl_xor(v, d));
  return v;
}
__device__ __forceinline__ float sigmoidf_(float x) { return 1.f / (1.f + expf(-x)); }
__device__ __forceinline__ float softplusf_(float x) {
  return fmaxf(x, 0.f) + log1pf(expf(-fabsf(x)));
}
__device__ __forceinline__ float gelu_t(float x) {
  float u = 0.7978845608028654f * (x + 0.044715f * x * x * x);
  return 0.5f * x * (1.f + tanhf(u));
}
__device__ __forceinline__ bool better(float v, int h, float V, int H) {
  return (v > V) || (v == V && h < H);
}
// value-returning split helpers (vector elements can't bind to refs)
__device__ __forceinline__ _Float16 hi16(float v) { return (_Float16)v; }
__device__ __forceinline__ _Float16 lo16(float v, _Float16 h) {
  return (_Float16)(v - (float)h);
}
__device__ __forceinline__ void split8(const float4& a, const float4& b,
                                       f16x8& vh, f16x8& vl) {
  _Float16 h0 = hi16(a.x), h1 = hi16(a.y), h2 = hi16(a.z), h3 = hi16(a.w);
  _Float16 h4 = hi16(b.x), h5 = hi16(b.y), h6 = hi16(b.z), h7 = hi16(b.w);
  vh[0] = h0; vh[1] = h1; vh[2] = h2; vh[3] = h3;
  vh[4] = h4; vh[5] = h5; vh[6] = h6; vh[7] = h7;
  vl[0] = lo16(a.x, h0); vl[1] = lo16(a.y, h1);
  vl[2] = lo16(a.z, h2); vl[3] = lo16(a.w, h3);
  vl[4] = lo16(b.x, h4); vl[5] = lo16(b.y, h5);
  vl[6] = lo16(b.z, h6); vl[7] = lo16(b.w, h7);
}

// =====================================================================
// k0x: split X into fp16 hi/lo, packed per (mb,kk) 8 KB chunks with the
// bank-conflict XOR swizzle baked in: byte(r,kb)=r*64+16*(kb^((r>>1)&3))
// thread t -> (mb,kk,r,kb): 8 consecutive k values = one 16 B dst block
// =====================================================================
__global__ __launch_bounds__(256) void k0x_split(const float* __restrict__ x,
                                                 unsigned char* __restrict__ xah,
                                                 unsigned char* __restrict__ xal) {
  int t = blockIdx.x * 256 + threadIdx.x;  // 1,048,576 total
  int kb = t & 3, r = (t >> 2) & 127, kk = (t >> 9) & 15, mb = t >> 13;
  const float* src = x + (size_t)(mb * 128 + r) * NH + kk * 32 + kb * 8;
  float4 a = *(const float4*)src;
  float4 b = *(const float4*)(src + 4);
  f16x8 vh, vl;
  split8(a, b, vh, vl);
  size_t off = (size_t)(mb * 16 + kk) * 8192 + r * 64 + 16 * (kb ^ ((r >> 1) & 3));
  *(f16x8*)(xah + off) = vh;
  *(f16x8*)(xal + off) = vl;
}

// =====================================================================
// k0w: pack the 7 weight streams into fp16 hi/lo B-chunks per (hg,kk):
// [7 streams x 16 h][32 k], 7168 B each, same baked swizzle.
// stream order: delta,gamma,kernel,i,f,o,mem
// =====================================================================
__global__ __launch_bounds__(256) void k0w_pack(
    const float* __restrict__ in_proj_w, const float* __restrict__ kernel_w,
    const float* __restrict__ mem_gate_w, const float* __restrict__ unified,
    unsigned char* __restrict__ wbh, unsigned char* __restrict__ wbl) {
  int t = blockIdx.x * 256 + threadIdx.x;  // 229,376 total
  int kb = t & 3;
  int rest = t >> 2;
  int v = rest % 112;
  int rest2 = rest / 112;
  int kk = rest2 & 15, hg = rest2 >> 4;
  int j = v >> 4, n = v & 15;
  int h = hg * 16 + n;
  int k = kk * 32 + kb * 8;
  const float* src;
  switch (j) {
    case 0: src = in_proj_w + (size_t)h * NH + k; break;
    case 1: src = in_proj_w + (size_t)(512 + h) * NH + k; break;
    case 2: src = kernel_w + (size_t)h * NH + k; break;
    case 3: src = mem_gate_w + (size_t)h * NH + k; break;
    case 4: src = mem_gate_w + (size_t)(512 + h) * NH + k; break;
    case 5: src = mem_gate_w + (size_t)(1024 + h) * NH + k; break;
    default: src = unified + (size_t)h * 1536 + k; break;
  }
  float4 a = *(const float4*)src;
  float4 b = *(const float4*)(src + 4);
  f16x8 vh, vl;
  split8(a, b, vh, vl);
  size_t off = (size_t)(hg * 16 + kk) * 7168 + v * 64 + 16 * (kb ^ ((v >> 1) & 3));
  *(f16x8*)(wbh + off) = vh;
  *(f16x8*)(wbl + off) = vl;
}

// =====================================================================
// k1_mfma: C[128 rows x (7 streams x 16 h)] via fp16x3 compensated MFMA
// (xh*wh + xh*wl + xl*wh), fp32 accumulate. global_load_lds staging into
// single LDS buffer, 16 K-steps of 32. Fused SSM+memory epilogue.
// 4 waves: wave w owns rows w*32..w*32+31 (2 m-tiles), all 7 streams.
// =====================================================================
__global__ __launch_bounds__(256, 2) void k1_mfma(
    const unsigned char* __restrict__ xah, const unsigned char* __restrict__ xal,
    const unsigned char* __restrict__ wbh, const unsigned char* __restrict__ wbl,
    const float* __restrict__ ssm_state, const float* __restrict__ memory0,
    const float* __restrict__ in_proj_b, const float* __restrict__ mem_scales,
    float* __restrict__ ssm_out, float* __restrict__ combined) {
  __shared__ __align__(16) unsigned char lds[30720];  // Ah 8K | Al 8K | Bh 7K | Bl 7K

  const int tid = threadIdx.x;
  const int wave = tid >> 6, lane = tid & 63;
  const int m16 = lane & 15, kb4 = lane >> 4;
  const int mb = blockIdx.x, hg = blockIdx.y;

  f32x4 acc[2][7];
#pragma unroll
  for (int mt = 0; mt < 2; ++mt)
#pragma unroll
    for (int j = 0; j < 7; ++j) acc[mt][j] = (f32x4){0.f, 0.f, 0.f, 0.f};

  const int sw = 16 * (kb4 ^ ((m16 >> 1) & 3));
  const int byA0 = (wave * 32 + m16) * 64 + sw;
  const int byA1 = byA0 + 16 * 64;

  for (int kk = 0; kk < 16; ++kk) {
    const unsigned char* ah_c = xah + (size_t)(mb * 16 + kk) * 8192;
    const unsigned char* al_c = xal + (size_t)(mb * 16 + kk) * 8192;
    const unsigned char* bh_c = wbh + (size_t)(hg * 16 + kk) * 7168;
    const unsigned char* bl_c = wbl + (size_t)(hg * 16 + kk) * 7168;
#pragma unroll
    for (int u = 0; u < 8; ++u) {
      int t = u * 4 + wave;
      if (t < 30) {
        const unsigned char* g;
        unsigned char* l;
        if (t < 8)       { g = ah_c + t * 1024;        l = lds + t * 1024; }
        else if (t < 16) { g = al_c + (t - 8) * 1024;  l = lds + 8192 + (t - 8) * 1024; }
        else if (t < 23) { g = bh_c + (t - 16) * 1024; l = lds + 16384 + (t - 16) * 1024; }
        else             { g = bl_c + (t - 23) * 1024; l = lds + 23552 + (t - 23) * 1024; }
        __builtin_amdgcn_global_load_lds(
            (const __attribute__((address_space(1))) unsigned int*)(g + lane * 16),
            (__attribute__((address_space(3))) unsigned int*)l, 16, 0, 0);
      }
    }
    __syncthreads();
    f16x8 ah0 = *(const f16x8*)(lds + byA0);
    f16x8 ah1 = *(const f16x8*)(lds + byA1);
    f16x8 al0 = *(const f16x8*)(lds + 8192 + byA0);
    f16x8 al1 = *(const f16x8*)(lds + 8192 + byA1);
#pragma unroll
    for (int j = 0; j < 7; ++j) {
      int byB = (j * 16 + m16) * 64 + sw;
      f16x8 bh = *(const f16x8*)(lds + 16384 + byB);
      f16x8 bl = *(const f16x8*)(lds + 23552 + byB);
      acc[0][j] = __builtin_amdgcn_mfma_f32_16x16x32_f16(ah0, bh, acc[0][j], 0, 0, 0);
      acc[0][j] = __builtin_amdgcn_mfma_f32_16x16x32_f16(ah0, bl, acc[0][j], 0, 0, 0);
      acc[0][j] = __builtin_amdgcn_mfma_f32_16x16x32_f16(al0, bh, acc[0][j], 0, 0, 0);
      acc[1][j] = __builtin_amdgcn_mfma_f32_16x16x32_f16(ah1, bh, acc[1][j], 0, 0, 0);
      acc[1][j] = __builtin_amdgcn_mfma_f32_16x16x32_f16(ah1, bl, acc[1][j], 0, 0, 0);
      acc[1][j] = __builtin_amdgcn_mfma_f32_16x16x32_f16(al1, bh, acc[1][j], 0, 0, 0);
    }
    __syncthreads();
  }

  // ---- epilogue ----
  float s0 = mem_scales[0], s1 = mem_scales[1], s2 = mem_scales[2], s3 = mem_scales[3];
  float smax = fmaxf(fmaxf(s0, s1), fmaxf(s2, s3));
  float e0 = expf(s0 - smax), e1 = expf(s1 - smax), e2 = expf(s2 - smax), e3 = expf(s3 - smax);
  float esum = e0 + e1 + e2 + e3;
  float sc0 = e0 / esum, sc1 = e1 / esum, sc2 = e2 / esum, sc3 = e3 / esum;
  float scsum = sc0 + sc1 + sc2 + sc3;

  const int h = hg * 16 + m16;
  const float bd = in_proj_b[h];
  const float bg = in_proj_b[512 + h];
#pragma unroll
  for (int mt = 0; mt < 2; ++mt) {
#pragma unroll
    for (int r = 0; r < 4; ++r) {
      int row = mb * 128 + wave * 32 + mt * 16 + kb4 * 4 + r;
      size_t idx = (size_t)row * NH + h;
      float draw = acc[mt][0][r] + bd;
      float graw = acc[mt][1][r] + bg;
      float sp = softplusf_(draw);
      float decay = expf(-sp);
      float kern = acc[mt][2][r];
      float ssm_new = ssm_state[idx] * decay + kern * (1.f - decay) * graw;
      float ig = sigmoidf_(acc[mt][3][r]);
      float fg = sigmoidf_(acc[mt][4][r]);
      float og = sigmoidf_(acc[mt][5][r]);
      float tl = tanhf(acc[mt][6][r]);
      float wm = sc0 * memory0[idx] + sc1 * memory0[(size_t)BH + idx] +
                 sc2 * memory0[2 * (size_t)BH + idx] + sc3 * memory0[3 * (size_t)BH + idx];
      float ms = og * (ig * tl * scsum + fg * wm);
      ssm_out[idx] = ssm_new;
      combined[idx] = ssm_new + ms;
    }
  }
}

// =====================================================================
// Fallback fp32 k1 (verified round 1) — used if ws_size < WS_NEED
// =====================================================================
__global__ __launch_bounds__(256, 2) void k1_fused_x(
    const float* __restrict__ x, const float* __restrict__ ssm_state,
    const float* __restrict__ memory0, const float* __restrict__ in_proj_w,
    const float* __restrict__ in_proj_b, const float* __restrict__ kernel_w,
    const float* __restrict__ unified, const float* __restrict__ mem_gate_w,
    const float* __restrict__ mem_scales, float* __restrict__ ssm_out,
    float* __restrict__ combined) {
  __shared__ __align__(16) float xs[64][20];
  __shared__ __align__(16) float wsh[448 * 16];

  const int tid = threadIdx.x;
  const int tc = tid & 63, rg = tid >> 6;
  const int rb0 = blockIdx.x * 64;
  const int h0 = blockIdx.y * 64;
  const int sx = (tc >> 1) & 3;

  float acc[16][7];
#pragma unroll
  for (int i = 0; i < 16; ++i)
#pragma unroll
    for (int j = 0; j < 7; ++j) acc[i][j] = 0.f;

  for (int k0 = 0; k0 < NH; k0 += 16) {
    {
      int r = tid >> 2, kq = tid & 3;
      float4 v = *(const float4*)(x + (size_t)(rb0 + r) * NH + k0 + kq * 4);
      *(float4*)(&xs[r][kq * 4]) = v;
    }
#pragma unroll
    for (int c4 = 0; c4 < 7; ++c4) {
      int l = tid >> 2, kq = tid & 3;
      int n = c4 * 64 + l;
      const float* wrow;
      switch (c4) {
        case 0: wrow = in_proj_w + (size_t)(h0 + l) * NH; break;
        case 1: wrow = in_proj_w + (size_t)(512 + h0 + l) * NH; break;
        case 2: wrow = kernel_w + (size_t)(h0 + l) * NH; break;
        case 3: wrow = mem_gate_w + (size_t)(h0 + l) * NH; break;
        case 4: wrow = mem_gate_w + (size_t)(512 + h0 + l) * NH; break;
        case 5: wrow = mem_gate_w + (size_t)(1024 + h0 + l) * NH; break;
        default: wrow = unified + (size_t)(h0 + l) * 1536; break;
      }
      float4 v = *(const float4*)(wrow + k0 + kq * 4);
      int slot = n * 4 + (kq ^ ((n >> 1) & 3));
      *((float4*)wsh + slot) = v;
    }
    __syncthreads();
#pragma unroll
    for (int kg = 0; kg < 4; ++kg) {
      float4 wv[7];
#pragma unroll
      for (int j = 0; j < 7; ++j) {
        int n = tc + 64 * j;
        wv[j] = *((const float4*)wsh + n * 4 + (kg ^ sx));
      }
#pragma unroll
      for (int i = 0; i < 16; ++i) {
        float4 xv = *(const float4*)(&xs[rg * 16 + i][kg * 4]);
#pragma unroll
        for (int j = 0; j < 7; ++j) {
          acc[i][j] = fmaf(xv.x, wv[j].x, acc[i][j]);
          acc[i][j] = fmaf(xv.y, wv[j].y, acc[i][j]);
          acc[i][j] = fmaf(xv.z, wv[j].z, acc[i][j]);
          acc[i][j] = fmaf(xv.w, wv[j].w, acc[i][j]);
        }
      }
    }
    __syncthreads();
  }

  float s0 = mem_scales[0], s1 = mem_scales[1], s2 = mem_scales[2], s3 = mem_scales[3];
  float sm = fmaxf(fmaxf(s0, s1), fmaxf(s2, s3));
  float e0 = expf(s0 - sm), e1 = expf(s1 - sm), e2 = expf(s2 - sm), e3 = expf(s3 - sm);
  float esum = e0 + e1 + e2 + e3;
  float sc0 = e0 / esum, sc1 = e1 / esum, sc2 = e2 / esum, sc3 = e3 / esum;
  float scsum = sc0 + sc1 + sc2 + sc3;

  const int h = h0 + tc;
  const float bd = in_proj_b[h];
  const float bg = in_proj_b[512 + h];
#pragma unroll
  for (int i = 0; i < 16; ++i) {
    int row = rb0 + rg * 16 + i;
    size_t idx = (size_t)row * NH + h;
    float draw = acc[i][0] + bd;
    float graw = acc[i][1] + bg;
    float sp = softplusf_(draw);
    float decay = expf(-sp);
    float kern = acc[i][2];
    float ssm_new = ssm_state[idx] * decay + kern * (1.f - decay) * graw;
    float ig = sigmoidf_(acc[i][3]);
    float fg = sigmoidf_(acc[i][4]);
    float og = sigmoidf_(acc[i][5]);
    float tl = tanhf(acc[i][6]);
    float wm = sc0 * memory0[idx] + sc1 * memory0[(size_t)BH + idx] +
               sc2 * memory0[2 * (size_t)BH + idx] + sc3 * memory0[3 * (size_t)BH + idx];
    float ms = og * (ig * tl * scsum + fg * wm);
    ssm_out[idx] = ssm_new;
    combined[idx] = ssm_new + ms;
  }
}

// =====================================================================
// k2: LayerNorm stats
// =====================================================================
__global__ __launch_bounds__(256) void k2_lnstats(const float* __restrict__ comb,
                                                  float* __restrict__ mu,
                                                  float* __restrict__ rsb) {
  int w = threadIdx.x >> 6, lane = threadIdx.x & 63;
  int row = blockIdx.x * 4 + w;
  const float* c = comb + (size_t)row * NH;
  float v[8];
  float s = 0.f;
#pragma unroll
  for (int q = 0; q < 8; ++q) { v[q] = c[lane + 64 * q]; s += v[q]; }
  s = wred_sum(s);
  float m = s * (1.f / 512.f);
  float s2 = 0.f;
#pragma unroll
  for (int q = 0; q < 8; ++q) { float d = v[q] - m; s2 += d * d; }
  s2 = wred_sum(s2);
  if (lane == 0) {
    mu[row] = m;
    rsb[row] = rsqrtf(s2 * (1.f / 512.f) + 1e-5f);
  }
}

// =====================================================================
// k3: routing GEMM + softmax/temp + clamp + top-2
// =====================================================================
__global__ __launch_bounds__(256, 2) void k3_route(
    const float* __restrict__ comb, const float* __restrict__ mu,
    const float* __restrict__ rsb, const float* __restrict__ unified,
    const float* __restrict__ lng, const float* __restrict__ lnb,
    int* __restrict__ i1o, int* __restrict__ i2o, float* __restrict__ q1o,
    float* __restrict__ q2o) {
  __shared__ __align__(16) float xs[32][20];
  __shared__ __align__(16) float wsh[512 * 16];
  __shared__ float mus[32], rss[32];

  const int tid = threadIdx.x;
  const int tc = tid & 63, rg = tid >> 6;
  const int rb0 = blockIdx.x * 32;
  const int sx = (tc >> 1) & 3;

  if (tid < 32) mus[tid] = mu[rb0 + tid];
  else if (tid < 64) rss[tid - 32] = rsb[rb0 + tid - 32];
  __syncthreads();

  float acc[8][8];
#pragma unroll
  for (int i = 0; i < 8; ++i)
#pragma unroll
    for (int j = 0; j < 8; ++j) acc[i][j] = 0.f;

  for (int k0 = 0; k0 < NH; k0 += 16) {
    if (tid < 128) {
      int r = tid >> 2, kq = tid & 3;
      float4 cv = *(const float4*)(comb + (size_t)(rb0 + r) * NH + k0 + kq * 4);
      float4 gv = *(const float4*)(lng + k0 + kq * 4);
      float4 bv = *(const float4*)(lnb + k0 + kq * 4);
      float mm = mus[r], rr = rss[r];
      float4 o;
      o.x = (cv.x - mm) * rr * gv.x + bv.x;
      o.y = (cv.y - mm) * rr * gv.y + bv.y;
      o.z = (cv.z - mm) * rr * gv.z + bv.z;
      o.w = (cv.w - mm) * rr * gv.w + bv.w;
      *(float4*)(&xs[r][kq * 4]) = o;
    }
#pragma unroll
    for (int c4 = 0; c4 < 8; ++c4) {
      int fidx = c4 * 256 + tid;
      int n = fidx >> 2, kq = fidx & 3;
      float4 v = *(const float4*)(unified + (size_t)n * 1536 + 512 + k0 + kq * 4);
      int slot = n * 4 + (kq ^ ((n >> 1) & 3));
      *((float4*)wsh + slot) = v;
    }
    __syncthreads();
#pragma unroll
    for (int kg = 0; kg < 4; ++kg) {
      float4 wv[8];
#pragma unroll
      for (int j = 0; j < 8; ++j) {
        int n = tc + 64 * j;
        wv[j] = *((const float4*)wsh + n * 4 + (kg ^ sx));
      }
#pragma unroll
      for (int i = 0; i < 8; ++i) {
        float4 xv = *(const float4*)(&xs[rg * 8 + i][kg * 4]);
#pragma unroll
        for (int j = 0; j < 8; ++j) {
          acc[i][j] = fmaf(xv.x, wv[j].x, acc[i][j]);
          acc[i][j] = fmaf(xv.y, wv[j].y, acc[i][j]);
          acc[i][j] = fmaf(xv.z, wv[j].z, acc[i][j]);
          acc[i][j] = fmaf(xv.w, wv[j].w, acc[i][j]);
        }
      }
    }
    __syncthreads();
  }

#pragma unroll 1
  for (int i = 0; i < 8; ++i) {
    int row = rb0 + rg * 8 + i;
    float z[8];
#pragma unroll
    for (int j = 0; j < 8; ++j) z[j] = acc[i][j] / 0.1f;
    float m = z[0];
#pragma unroll
    for (int j = 1; j < 8; ++j) m = fmaxf(m, z[j]);
    m = wred_max(m);
    float p[8];
    float ssum = 0.f;
#pragma unroll
    for (int j = 0; j < 8; ++j) { p[j] = expf(z[j] - m); ssum += p[j]; }
    ssum = wred_sum(ssum);
    float v1 = -1.f, v2 = -1.f;
    int h1 = 1 << 30, h2 = 1 << 30;
#pragma unroll
    for (int j = 0; j < 8; ++j) {
      float pc = fmaxf(p[j] / ssum, 1e-4f);
      int hh = tc + 64 * j;
      if (better(pc, hh, v1, h1)) { v2 = v1; h2 = h1; v1 = pc; h1 = hh; }
      else if (better(pc, hh, v2, h2)) { v2 = pc; h2 = hh; }
    }
#pragma unroll
    for (int d = 1; d < 64; d <<= 1) {
      float b1v = __shfl_xor(v1, d); int b1h = __shfl_xor(h1, d);
      float b2v = __shfl_xor(v2, d); int b2h = __shfl_xor(h2, d);
      float n1v, n2v; int n1h, n2h;
      if (better(v1, h1, b1v, b1h)) {
        n1v = v1; n1h = h1;
        if (better(v2, h2, b1v, b1h)) { n2v = v2; n2h = h2; }
        else { n2v = b1v; n2h = b1h; }
      } else {
        n1v = b1v; n1h = b1h;
        if (better(b2v, b2h, v1, h1)) { n2v = b2v; n2h = b2h; }
        else { n2v = v1; n2h = h1; }
      }
      v1 = n1v; h1 = n1h; v2 = n2v; h2 = n2h;
    }
    if (tc == 0) {
      float s = v1 + v2;
      i1o[row] = h1; i2o[row] = h2;
      q1o[row] = v1 / s; q2o[row] = v2 / s;
    }
  }
}

// =====================================================================
// k4: expert output scatter
// =====================================================================
__global__ __launch_bounds__(256) void k4_expert(
    const float* __restrict__ comb, const float* __restrict__ unified,
    const int* __restrict__ i1, const int* __restrict__ i2,
    const float* __restrict__ q1, const float* __restrict__ q2,
    float* __restrict__ eo) {
  int w = threadIdx.x >> 6, lane = threadIdx.x & 63;
  int row = blockIdx.x * 4 + w;
  int h1 = i1[row], h2 = i2[row];
  float a = q1[row], b = q2[row];
  const float* c = comb + (size_t)row * NH;
  const float* w1 = unified + (size_t)h1 * 1536 + 1024;
  const float* w2 = unified + (size_t)h2 * 1536 + 1024;
  float d1 = 0.f, d2 = 0.f;
#pragma unroll
  for (int q = 0; q < 8; ++q) {
    int k = lane + 64 * q;
    float cv = c[k];
    d1 += cv * w1[k];
    d2 += cv * w2[k];
  }
  d1 = wred_sum(d1);
  d2 = wred_sum(d2);
  float e1 = a * d1, e2 = b * d2;
  float* o = eo + (size_t)row * NH;
#pragma unroll
  for (int q = 0; q < 8; ++q) {
    int hh = lane + 64 * q;
    o[hh] = (hh == h1) ? e1 : ((hh == h2) ? e2 : 0.f);
  }
}

// =====================================================================
// k5: value/policy heads
// =====================================================================
__global__ __launch_bounds__(256, 2) void k5_heads(
    const float* __restrict__ comb, const float* __restrict__ vw1,
    const float* __restrict__ vb1, const float* __restrict__ vw2,
    const float* __restrict__ vb2, const float* __restrict__ pw1,
    const float* __restrict__ pb1, const float* __restrict__ pw2,
    const float* __restrict__ pb2, float* __restrict__ valo,
    float* __restrict__ polo, float* __restrict__ ento) {
  __shared__ __align__(16) float xs[32][20];
  __shared__ __align__(16) float wsh[512 * 16];
  __shared__ float bias_s[512];
  __shared__ float vw2_s[256];
  __shared__ float pw2_s[2048];

  const int tid = threadIdx.x;
  const int tc = tid & 63, rg = tid >> 6;
  const int rb0 = blockIdx.x * 32;
  const int sx = (tc >> 1) & 3;

  if (tid < 256) {
    bias_s[tid] = vb1[tid];
    bias_s[tid + 256] = pb1[tid];
    vw2_s[tid] = vw2[tid];
  }
#pragma unroll
  for (int q = 0; q < 8; ++q) pw2_s[tid + 256 * q] = pw2[tid + 256 * q];
  __syncthreads();

  float acc[8][8];
#pragma unroll
  for (int i = 0; i < 8; ++i)
#pragma unroll
    for (int j = 0; j < 8; ++j) acc[i][j] = 0.f;

  for (int k0 = 0; k0 < NH; k0 += 16) {
    if (tid < 128) {
      int r = tid >> 2, kq = tid & 3;
      float4 v = *(const float4*)(comb + (size_t)(rb0 + r) * NH + k0 + kq * 4);
      *(float4*)(&xs[r][kq * 4]) = v;
    }
#pragma unroll
    for (int c4 = 0; c4 < 8; ++c4) {
      int l = tid >> 2, kq = tid & 3;
      int n = c4 * 64 + l;
      const float* src = (c4 < 4) ? (vw1 + (size_t)n * NH) : (pw1 + (size_t)(n - 256) * NH);
      float4 v = *(const float4*)(src + k0 + kq * 4);
      int slot = n * 4 + (kq ^ ((n >> 1) & 3));
      *((float4*)wsh + slot) = v;
    }
    __syncthreads();
#pragma unroll
    for (int kg = 0; kg < 4; ++kg) {
      float4 wv[8];
#pragma unroll
      for (int j = 0; j < 8; ++j) {
        int n = tc + 64 * j;
        wv[j] = *((const float4*)wsh + n * 4 + (kg ^ sx));
      }
#pragma unroll
      for (int i = 0; i < 8; ++i) {
        float4 xv = *(const float4*)(&xs[rg * 8 + i][kg * 4]);
#pragma unroll
        for (int j = 0; j < 8; ++j) {
          acc[i][j] = fmaf(xv.x, wv[j].x, acc[i][j]);
          acc[i][j] = fmaf(xv.y, wv[j].y, acc[i][j]);
          acc[i][j] = fmaf(xv.z, wv[j].z, acc[i][j]);
          acc[i][j] = fmaf(xv.w, wv[j].w, acc[i][j]);
        }
      }
    }
    __syncthreads();
  }

  const float vb2v = vb2[0];
#pragma unroll 1
  for (int i = 0; i < 8; ++i) {
    int row = rb0 + rg * 8 + i;
    float gv[8];
#pragma unroll
    for (int j = 0; j < 8; ++j) gv[j] = gelu_t(acc[i][j] + bias_s[tc + 64 * j]);
    float vp = 0.f;
#pragma unroll
    for (int j = 0; j < 4; ++j) vp += gv[j] * vw2_s[tc + 64 * j];
    vp = wred_sum(vp);
    float val = vp + vb2v;
    float pol[8];
#pragma unroll
    for (int e = 0; e < 8; ++e) {
      float pp = 0.f;
#pragma unroll
      for (int j = 4; j < 8; ++j) pp += gv[j] * pw2_s[e * 256 + tc + 64 * j - 256];
      pp = wred_sum(pp);
      pol[e] = pp + pb2[e];
    }
    float m = pol[0];
#pragma unroll
    for (int e = 1; e < 8; ++e) m = fmaxf(m, pol[e]);
    float se = 0.f;
#pragma unroll
    for (int e = 0; e < 8; ++e) se += expf(pol[e] - m);
    float lse = m + logf(se);
    float ent = 0.f;
#pragma unroll
    for (int e = 0; e < 8; ++e) {
      float lp = pol[e] - lse;
      ent -= expf(lp) * lp;
    }
    if (tc == 0) {
      valo[row] = val;
      ento[row] = ent;
#pragma unroll
      for (int e = 0; e < 8; ++e) polo[(size_t)row * 8 + e] = pol[e];
    }
  }
}

// =====================================================================
extern "C" void kernel_launch(void* const* d_in, const int* in_sizes, int n_in,
                              void* d_out, int out_size, void* d_ws, size_t ws_size,
                              hipStream_t stream) {
  const float* x          = (const float*)d_in[0];
  const float* ssm_state  = (const float*)d_in[1];
  const float* memory0    = (const float*)d_in[2];
  const float* in_proj_w  = (const float*)d_in[3];
  const float* in_proj_b  = (const float*)d_in[4];
  const float* kernel_w   = (const float*)d_in[5];
  const float* unified    = (const float*)d_in[6];
  const float* mem_gate_w = (const float*)d_in[7];
  const float* mem_scales = (const float*)d_in[8];
  const float* ln_g       = (const float*)d_in[9];
  const float* ln_b       = (const float*)d_in[10];
  const float* vw1        = (const float*)d_in[11];
  const float* vb1        = (const float*)d_in[12];
  const float* vw2        = (const float*)d_in[13];
  const float* vb2        = (const float*)d_in[14];
  const float* pw1        = (const float*)d_in[15];
  const float* pb1        = (const float*)d_in[16];
  const float* pw2        = (const float*)d_in[17];
  const float* pb2        = (const float*)d_in[18];

  float* eo  = (float*)d_out;
  float* ssm = eo + (size_t)BH;
  float* val = ssm + (size_t)BH;
  float* pol = val + NB;
  float* ent = pol + (size_t)NB * NE;

  unsigned char* ws = (unsigned char*)d_ws;
  float* combined = (float*)(ws + OFF_COMB);
  float* mu = (float*)(ws + OFF_MU);
  float* rs = (float*)(ws + OFF_RS);
  int* i1 = (int*)(ws + OFF_I1);
  int* i2 = (int*)(ws + OFF_I2);
  float* q1 = (float*)(ws + OFF_Q1);
  float* q2 = (float*)(ws + OFF_Q2);

  if (ws_size >= WS_NEED) {
    unsigned char* xah = ws + OFF_XAH;
    unsigned char* xal = ws + OFF_XAL;
    unsigned char* wbh = ws + OFF_WBH;
    unsigned char* wbl = ws + OFF_WBL;
    hipLaunchKernelGGL(k0x_split, dim3(4096), dim3(256), 0, stream, x, xah, xal);
    hipLaunchKernelGGL(k0w_pack, dim3(896), dim3(256), 0, stream, in_proj_w,
                       kernel_w, mem_gate_w, unified, wbh, wbl);
    hipLaunchKernelGGL(k1_mfma, dim3(128, 32), dim3(256), 0, stream, xah, xal,
                       wbh, wbl, ssm_state, memory0, in_proj_b, mem_scales, ssm,
                       combined);
  } else {
    hipLaunchKernelGGL(k1_fused_x, dim3(NB / 64, NH / 64), dim3(256), 0, stream,
                       x, ssm_state, memory0, in_proj_w, in_proj_b, kernel_w,
                       unified, mem_gate_w, mem_scales, ssm, combined);
  }
  hipLaunchKernelGGL(k2_lnstats, dim3(NB / 4), dim3(256), 0, stream, combined, mu, rs);
  hipLaunchKernelGGL(k3_route, dim3(NB / 32), dim3(256), 0, stream, combined, mu,
                     rs, unified, ln_g, ln_b, i1, i2, q1, q2);
  hipLaunchKernelGGL(k4_expert, dim3(NB / 4), dim3(256), 0, stream, combined,
                     unified, i1, i2, q1, q2, eo);
  hipLaunchKernelGGL(k5_heads, dim3(NB / 32), dim3(256), 0, stream, combined, vw1,
                     vb1, vw2, vb2, pw1, pb1, pw2, pb2, val, pol, ent);
}